// Round 19
// baseline (127.487 us; speedup 1.0000x reference)
//
#include <hip/hip_runtime.h>
#include <hip/hip_bf16.h>

#define LSEQ   16384
#define BATCH  32
#define NBS    64              // B*2 sequences
#define NW     8000
#define CHUNK  448             // output rows per block
#define NCHK   37              // ceil(16384/448)
#define ROWS   538             // plane rows: seq [base-32, base+506)
#define NT12   12              // k-steps: 6 lo (wi 0-7) + 6 hi (wi 8-9)

typedef short v8s __attribute__((ext_vector_type(8)));   // 8 bf16 = 4 VGPR
typedef short v4s __attribute__((ext_vector_type(4)));   // 4 bf16 = 2 VGPR
typedef float v4f __attribute__((ext_vector_type(4)));   // MFMA acc
typedef _Float16 hf2 __attribute__((ext_vector_type(2)));  // packed f16 pair

__device__ __forceinline__ unsigned short f2bf(float f) {   // RTNE f32->bf16
  unsigned u = __float_as_uint(f);
  unsigned r = u + 0x7FFFu + ((u >> 16) & 1u);
  return (unsigned short)(r >> 16);
}
__device__ __forceinline__ unsigned short cvt_bf16(float v) {  // HW cvt
  __hip_bfloat16 hb = __float2bfloat16(v);
  unsigned short us;
  __builtin_memcpy(&us, &hb, 2);
  return us;
}

// ---------------------------------------------------------------------------
// Prep: blocks 0..31 build bf16 emb table [NW+1][16] (elems 10..15 = 0);
// blocks 32..40 build MFMA B-fragments for the SPLIT-K ordering:
//   steps t=0..5 : k-slot s=8g+j -> (kh = 4t+g,     wi = j)      [lo, b128]
//   steps t=6..11: k-slot s=8g+j -> (kh = 4(t-6)+g, wi = 8+j)    [hi, b64+dup]
// B[s][col] = W[kh][wi-col+10] if (wi<10 && col<10 && kh<22 && kw in [0,22))
// else 0. kh 22,23 are pad rows (B=0; A reads real-but-ignored data).
// 3*12*64 = 2304 entries = exactly 9 blocks (sizing re-checked: r16 lesson).
// ---------------------------------------------------------------------------
__global__ __launch_bounds__(256) void prep_kernel(
    const float* __restrict__ emb, const float* __restrict__ w1,
    const float* __restrict__ w2, const float* __restrict__ w3,
    unsigned short* __restrict__ emb16, unsigned short* __restrict__ bh) {
  int bid = blockIdx.x;
  if (bid < 32) {
    int r = bid * 256 + threadIdx.x;
    if (r > NW) return;
    const float2* er = reinterpret_cast<const float2*>(emb + r * 10);
    float v[10];
#pragma unroll
    for (int k = 0; k < 5; ++k) { float2 t2 = er[k]; v[2 * k] = t2.x; v[2 * k + 1] = t2.y; }
    v8s lo8 = (v8s)0, hi8 = (v8s)0;
#pragma unroll
    for (int j = 0; j < 8; ++j) lo8[j] = (short)f2bf(v[j]);
    hi8[0] = (short)f2bf(v[8]);
    hi8[1] = (short)f2bf(v[9]);
    v8s* dst = reinterpret_cast<v8s*>(emb16 + r * 16);
    dst[0] = lo8;
    dst[1] = hi8;
  } else {
    int idx = (bid - 32) * 256 + threadIdx.x;   // (stage*12 + t)*64 + lane
    if (idx >= 3 * NT12 * 64) return;
    int lane = idx & 63, rest = idx >> 6;
    int t = rest % NT12, stage = rest / NT12;
    const float* W = (stage == 0) ? w1 : (stage == 1) ? w2 : w3;
    int col = lane & 15;
    int g = lane >> 4;
#pragma unroll
    for (int j = 0; j < 8; ++j) {
      int kh = (t < 6) ? (4 * t + g) : (4 * (t - 6) + g);
      int wi = (t < 6) ? j : (8 + j);
      int kw = wi - col + 10;
      float v = (wi < 10 && col < 10 && kh < 22 && kw >= 0 && kw < 22)
                    ? W[kh * 22 + kw] : 0.0f;
      bh[idx * 8 + j] = f2bf(v);
    }
  }
}

// ---------------------------------------------------------------------------
// Packed-pair (two channels per u32, f16x2) bitonic primitives (r12-verified).
// ---------------------------------------------------------------------------
__device__ __forceinline__ unsigned h2max_u(unsigned a, unsigned b) {
  hf2 r = __builtin_elementwise_max(__builtin_bit_cast(hf2, a),
                                    __builtin_bit_cast(hf2, b));
  return __builtin_bit_cast(unsigned, r);
}
__device__ __forceinline__ unsigned h2min_u(unsigned a, unsigned b) {
  hf2 r = __builtin_elementwise_min(__builtin_bit_cast(hf2, a),
                                    __builtin_bit_cast(hf2, b));
  return __builtin_bit_cast(unsigned, r);
}
__device__ __forceinline__ unsigned bsort64_h2(unsigned v, int lane) {
#pragma unroll
  for (int k = 2; k <= 64; k <<= 1) {
#pragma unroll
    for (int j = k >> 1; j > 0; j >>= 1) {
      unsigned o = __shfl_xor(v, j, 64);
      bool keepmax = (((lane & k) == 0) == ((lane & j) == 0));
      unsigned mx = h2max_u(v, o), mn = h2min_u(v, o);
      v = keepmax ? mx : mn;
    }
  }
  return v;
}
__device__ __forceinline__ unsigned bmerge64_h2(unsigned a, unsigned b, int lane) {
  unsigned rb = __shfl(b, 63 - lane, 64);
  unsigned m = h2max_u(a, rb);
#pragma unroll
  for (int j = 32; j > 0; j >>= 1) {
    unsigned o = __shfl_xor(m, j, 64);
    unsigned mx = h2max_u(m, o), mn = h2min_u(m, o);
    m = ((lane & j) == 0) ? mx : mn;
  }
  return m;
}

// ---------------------------------------------------------------------------
// Fused 3-layer conv via bf16 MFMA, SPLIT-K LDS layout:
//   loPlane [538][8]  (stride 8 ushorts = 16B): elems 0-7, b128 reads.
//   hiPlane [538][4]  (stride 4 ushorts =  8B): elems 8,9,0,0; b64 reads,
//     start banks 2r mod 32 -> 16 distinct -> conflict-free; v8s = dup(b64)
//     is exact because B rows for wi>=10 are zero and dup values are finite.
// 12 k-steps/tile (6 lo + 6 hi) vs r13's 11, but A-read LDS cycles drop ~35%
// and zero-pad bytes are no longer fetched. Epilogue/topk as r13.
// ---------------------------------------------------------------------------
__global__ __launch_bounds__(512, 6) void conv_fused_kernel(
    const int* __restrict__ inputs, const unsigned short* __restrict__ emb16,
    const float* __restrict__ b1, const float* __restrict__ b2,
    const float* __restrict__ b3,
    const unsigned short* __restrict__ bh,
    unsigned* __restrict__ candp /* [NBS*5][NCHK][50] packed */) {
  __shared__ unsigned short loP[ROWS * 8];   // 8608 B
  __shared__ unsigned short hiP[ROWS * 4];   // 4304 B

  int blk = blockIdx.x;
  int bs = blk / NCHK;
  int chunk = blk - bs * NCHK;
  int base = chunk * CHUNK;
  int tid = threadIdx.x;
  int lane = tid & 63, wave = tid >> 6;

  // ---- gather: bf16 emb rows for seq [base-32, base+506) ----
  const int* tokp = inputs + bs * LSEQ;
  for (int i = tid; i < ROWS; i += 512) {
    int seq = base - 32 + i;
    v8s lo8 = (v8s)0;
    v4s h4 = (v4s)0;
    if ((unsigned)seq < (unsigned)LSEQ) {
      int tok = tokp[seq];
      lo8 = *reinterpret_cast<const v8s*>(emb16 + tok * 16);
      h4 = *reinterpret_cast<const v4s*>(emb16 + tok * 16 + 8);  // [e8,e9,0,0]
    }
    *reinterpret_cast<v8s*>(&loP[i * 8]) = lo8;
    *reinterpret_cast<v4s*>(&hiP[i * 4]) = h4;
  }
  __syncthreads();

  // lane-constant row base: out-row (l&15) + kh-subgroup (l>>4) - 10 + 32
  const int rowBase = (lane & 15) + (lane >> 4) + 22;
  const int col = lane & 15;
  const int rbase = (lane >> 4) * 4;

#pragma unroll 1
  for (int stage = 0; stage < 3; ++stage) {
    const int lo = (stage == 0) ? -20 : (stage == 1) ? -10 : 0;
    const int ntiles = (stage == 0) ? 32 : (stage == 1) ? 30 : 28;
    const float bias = (stage == 0) ? b1[0] : (stage == 1) ? b2[0] : b3[0];
    const int nt = (ntiles - wave + 7) >> 3;     // tiles wave+8m, m<nt

    v4f acc[4];
#pragma unroll
    for (int m = 0; m < 4; ++m)
#pragma unroll
      for (int j = 0; j < 4; ++j) acc[m][j] = 0.0f;

    const v8s* bhf = reinterpret_cast<const v8s*>(bh) + (stage * NT12) * 64 + lane;
    v8s bhc = bhf[0];

#pragma unroll 1
    for (int t = 0; t < NT12; ++t) {
      v8s bhn = bhc;
      if (t < NT12 - 1) bhn = bhf[(t + 1) * 64];
      if (t < 6) {
        const int toff = (rowBase + 4 * t) * 8;
#pragma unroll
        for (int m = 0; m < 4; ++m) {
          if (m < nt) {
            int r0 = lo + (wave + 8 * m) * 16;
            v8s a = *reinterpret_cast<const v8s*>(&loP[toff + r0 * 8]);
            acc[m] = __builtin_amdgcn_mfma_f32_16x16x32_bf16(a, bhc, acc[m], 0, 0, 0);
          }
        }
      } else {
        const int toff = (rowBase + 4 * (t - 6)) * 4;
#pragma unroll
        for (int m = 0; m < 4; ++m) {
          if (m < nt) {
            int r0 = lo + (wave + 8 * m) * 16;
            v4s h = *reinterpret_cast<const v4s*>(&hiP[toff + r0 * 4]);
            v8s a = __builtin_shufflevector(h, h, 0, 1, 2, 3, 0, 1, 2, 3);
            acc[m] = __builtin_amdgcn_mfma_f32_16x16x32_bf16(a, bhc, acc[m], 0, 0, 0);
          }
        }
      }
      bhc = bhn;
    }
    __syncthreads();   // all reads complete before in-place writes

#pragma unroll
    for (int m = 0; m < 4; ++m) {
      if (m < nt) {
        int r0 = lo + (wave + 8 * m) * 16;
#pragma unroll
        for (int j = 0; j < 4; ++j) {
          int rloc = r0 + rbase + j;
          int seq = base + rloc;
          unsigned short us = cvt_bf16(fmaxf(acc[m][j] + bias, 0.0f));
          bool ok = (col < 10) && ((unsigned)seq < (unsigned)LSEQ);
          unsigned short w = ok ? us : (unsigned short)0;
          if (col < 8)
            loP[(rloc + 32) * 8 + col] = w;
          else if (col < 10)
            hiP[(rloc + 32) * 4 + (col - 8)] = w;
        }
      }
    }
    __syncthreads();
  }

  // ---- per-chunk exact top-50, one packed channel-pair stream per wave ----
  if (wave < 5) {
    int p = wave;                              // cols 2p, 2p+1
    unsigned x[7];
#pragma unroll
    for (int s = 0; s < 7; ++s) {
      int row = 32 + s * 64 + lane;
      unsigned w = (p < 4)
          ? *reinterpret_cast<const unsigned*>(&loP[row * 8 + 2 * p])
          : *reinterpret_cast<const unsigned*>(&hiP[row * 4]);
      float flo = __uint_as_float(w << 16);          // bf16 lo -> f32 (exact)
      float fhi = __uint_as_float(w & 0xFFFF0000u);  // bf16 hi -> f32 (exact)
      hf2 h;
      h[0] = (_Float16)flo;                          // f32 -> f16 (exact here)
      h[1] = (_Float16)fhi;
      x[s] = __builtin_bit_cast(unsigned, h);
    }
#pragma unroll
    for (int s = 0; s < 7; ++s) x[s] = bsort64_h2(x[s], lane);
    unsigned y0 = bmerge64_h2(x[0], x[1], lane);
    unsigned y1 = bmerge64_h2(x[2], x[3], lane);
    unsigned y2 = bmerge64_h2(x[4], x[5], lane);
    unsigned z0 = bmerge64_h2(y0, y1, lane);
    unsigned z1 = bmerge64_h2(y2, x[6], lane);
    unsigned t  = bmerge64_h2(z0, z1, lane);
    if (lane < 50)
      candp[((bs * 5 + p) * NCHK + chunk) * 50 + lane] = t;
  }
}

// ---------------------------------------------------------------------------
// MHA with fused candidate merge (r18-verified, byte-identical): batched
// independent loads then pure-VALU 36-step bitonic-merge chain (exact).
// ---------------------------------------------------------------------------
__global__ __launch_bounds__(256) void mha_kernel(
    const unsigned* __restrict__ candp,
    const float* __restrict__ wq, const float* __restrict__ bq,
    const float* __restrict__ wk, const float* __restrict__ bk,
    const float* __restrict__ wv, const float* __restrict__ bv,
    const float* __restrict__ wo, const float* __restrict__ bo,
    const float* __restrict__ wf, const float* __restrict__ bf,
    float* __restrict__ out) {
  __shared__ float f[2][50][10];
  __shared__ float Qm[50][2][10];
  __shared__ float Km[50][2][10];
  __shared__ float Vm[50][2][10];
  __shared__ float A2[2][50][50];
  __shared__ float Abar[2][50];
  __shared__ float OS[2][10];
  __shared__ float rr[10];

  int blk = blockIdx.x, b = blk >> 1, dir = blk & 1;
  int qs = dir, ks = dir ^ 1;
  int tid = threadIdx.x;
  int lane = tid & 63, wave = tid >> 6;

  // ---- merge: stream s = s2*5 + p (sequence bs = 2b + s2, channels 2p,2p+1)
  for (int s = wave; s < 10; s += 4) {
    int s2 = s / 5, p = s - s2 * 5;
    int bs = 2 * b + s2;
    const unsigned* src = candp + ((bs * 5 + p) * NCHK) * 50;
    unsigned v[NCHK];
    if (lane < 50) {
#pragma unroll
      for (int c = 0; c < NCHK; ++c) v[c] = src[c * 50 + lane];   // independent
    } else {
#pragma unroll
      for (int c = 0; c < NCHK; ++c) v[c] = 0u;
    }
    unsigned acc = v[0];
#pragma unroll
    for (int c = 1; c < NCHK; ++c)
      acc = bmerge64_h2(acc, v[c], lane);      // pure-VALU chain
    if (lane < 50) {
      hf2 h = __builtin_bit_cast(hf2, acc);
      f[s2][lane][2 * p + 0] = (float)h[0];
      f[s2][lane][2 * p + 1] = (float)h[1];
    }
  }
  __syncthreads();

  for (int i = tid; i < 1000; i += 256) {
    int q = i / 20, rem = i - q * 20;
    int h = rem / 10, e = rem - h * 10;
    const float* fq = f[qs][q];
    const float* fk = f[ks][q];
    float aq = bq[h * 10 + e], ak = bk[h * 10 + e], av = bv[h * 10 + e];
#pragma unroll
    for (int dd = 0; dd < 10; ++dd) {
      int wIdx = dd * 20 + h * 10 + e;
      aq = fmaf(fq[dd], wq[wIdx], aq);
      ak = fmaf(fk[dd], wk[wIdx], ak);
      av = fmaf(fk[dd], wv[wIdx], av);
    }
    Qm[q][h][e] = aq; Km[q][h][e] = ak; Vm[q][h][e] = av;
  }
  __syncthreads();

  for (int row = tid; row < 100; row += 256) {
    int h = row / 50, q = row - h * 50;
    const float* Qr = Qm[q][h];
    float lg[50], m = -1e30f;
#pragma unroll
    for (int s = 0; s < 50; ++s) {
      const float* Kr = Km[s][h];
      float t = 0.0f;
#pragma unroll
      for (int e = 0; e < 10; ++e) t = fmaf(Qr[e], Kr[e], t);
      t *= 0.31622776601683794f;   // 1/sqrt(10)
      lg[s] = t; m = fmaxf(m, t);
    }
    float sum = 0.0f;
#pragma unroll
    for (int s = 0; s < 50; ++s) { float p = __expf(lg[s] - m); lg[s] = p; sum += p; }
    float inv = 1.0f / sum;
#pragma unroll
    for (int s = 0; s < 50; ++s) A2[h][q][s] = lg[s] * inv;
  }
  __syncthreads();

  for (int i = tid; i < 100; i += 256) {
    int h = i / 50, s = i - h * 50;
    float t = 0.0f;
#pragma unroll
    for (int q = 0; q < 50; ++q) t += A2[h][q][s];
    Abar[h][s] = t;
  }
  __syncthreads();
  if (tid < 20) {
    int h = tid / 10, e = tid - h * 10;
    float t = 0.0f;
#pragma unroll
    for (int s = 0; s < 50; ++s) t += Abar[h][s] * Vm[s][h][e];
    OS[h][e] = t;
  }
  __syncthreads();
  if (tid < 10) {
    int dc = tid;
    float t = 50.0f * bo[dc];
#pragma unroll
    for (int h = 0; h < 2; ++h)
#pragma unroll
      for (int e = 0; e < 10; ++e) t = fmaf(OS[h][e], wo[h * 100 + e * 10 + dc], t);
    rr[dc] = t;
  }
  __syncthreads();
  if (tid == 0) {
    float l0 = bf[0], l1 = bf[1];
#pragma unroll
    for (int dd = 0; dd < 10; ++dd) {
      l0 = fmaf(rr[dd], wf[dd * 2 + 0], l0);
      l1 = fmaf(rr[dd], wf[dd * 2 + 1], l1);
    }
    float m = fmaxf(l0, l1);
    float e0 = expf(l0 - m), e1 = expf(l1 - m);
    float inv = 1.0f / (e0 + e1);
    out[(b * 2 + dir) * 2 + 0] = e0 * inv;
    out[(b * 2 + dir) * 2 + 1] = e1 * inv;
  }
}

// ---------------------------------------------------------------------------
extern "C" void kernel_launch(void* const* d_in, const int* in_sizes, int n_in,
                              void* d_out, int out_size, void* d_ws, size_t ws_size,
                              hipStream_t stream) {
  const int*   inputs = (const int*)d_in[0];
  const float* emb = (const float*)d_in[1];
  const float* w1 = (const float*)d_in[2];
  const float* b1 = (const float*)d_in[3];
  const float* w2 = (const float*)d_in[4];
  const float* b2 = (const float*)d_in[5];
  const float* w3 = (const float*)d_in[6];
  const float* b3 = (const float*)d_in[7];
  const float* wq = (const float*)d_in[8];
  const float* bq = (const float*)d_in[9];
  const float* wk = (const float*)d_in[10];
  const float* bk = (const float*)d_in[11];
  const float* wv = (const float*)d_in[12];
  const float* bv = (const float*)d_in[13];
  const float* wo = (const float*)d_in[14];
  const float* bo = (const float*)d_in[15];
  const float* wf = (const float*)d_in[16];
  const float* bf = (const float*)d_in[17];
  float* out = (float*)d_out;

  unsigned* candp = (unsigned*)((float*)d_ws + 32768);   // 64*5*37*50 u32
  unsigned short* bh = (unsigned short*)((float*)d_ws + 1216768);   // 2304*8 u16
  unsigned short* emb16 = bh + 18432;                 // 8001*16 u16 (16B-aligned)

  // 41 blocks: 32 emb + 9 bfrag (3*12*64 = 2304 entries = 9*256 exactly).
  hipLaunchKernelGGL(prep_kernel, dim3(41), dim3(256), 0, stream,
                     emb, w1, w2, w3, emb16, bh);
  hipLaunchKernelGGL(conv_fused_kernel, dim3(NBS * NCHK), dim3(512), 0, stream,
                     inputs, emb16, b1, b2, b3, bh, candp);
  hipLaunchKernelGGL(mha_kernel, dim3(NBS), dim3(256), 0, stream,
                     candp, wq, bq, wk, bk, wv, bv, wo, bo, wf, bf, out);
}

// Round 20
// 119.026 us; speedup vs baseline: 1.0711x; 1.0711x over previous
//
#include <hip/hip_runtime.h>
#include <hip/hip_bf16.h>

#define LSEQ   16384
#define BATCH  32
#define NBS    64              // B*2 sequences
#define NW     8000
#define CHUNK  448             // output rows per block
#define NCHK   37              // ceil(16384/448)
#define ROWS   536             // plane rows: seq [base-32, base+504)
#define RS     20              // row stride in ushorts (40B = 10 dwords -> 16 start banks)

typedef short v8s __attribute__((ext_vector_type(8)));   // 8 bf16 = 4 VGPR
typedef short v4s __attribute__((ext_vector_type(4)));   // 4 bf16 = 2 VGPR
typedef float v4f __attribute__((ext_vector_type(4)));   // MFMA acc
typedef _Float16 hf2 __attribute__((ext_vector_type(2)));  // packed f16 pair

__device__ __forceinline__ unsigned short f2bf(float f) {   // RTNE f32->bf16
  unsigned u = __float_as_uint(f);
  unsigned r = u + 0x7FFFu + ((u >> 16) & 1u);
  return (unsigned short)(r >> 16);
}
__device__ __forceinline__ unsigned short cvt_bf16(float v) {  // HW cvt
  __hip_bfloat16 hb = __float2bfloat16(v);
  unsigned short us;
  __builtin_memcpy(&us, &hb, 2);
  return us;
}

// ---------------------------------------------------------------------------
// Prep (r13/r17/r18-verified): blocks 0..31 build bf16 emb table [NW+1][16];
// blocks 32..40 build MFMA B-fragments (3*11*64 = 2112 entries -> 9 blocks).
// B[k=kh*16+wi][n] = W[kh][wi-n+10] (0 outside / n>=10); B-operand layout:
// lane l holds B[k][col=l&15], kh=2t+(l>>5), wi0=((l>>4)&1)*8, j=0..7.
// ---------------------------------------------------------------------------
__global__ __launch_bounds__(256) void prep_kernel(
    const float* __restrict__ emb, const float* __restrict__ w1,
    const float* __restrict__ w2, const float* __restrict__ w3,
    unsigned short* __restrict__ emb16, unsigned short* __restrict__ bh) {
  int bid = blockIdx.x;
  if (bid < 32) {
    int r = bid * 256 + threadIdx.x;
    if (r > NW) return;
    const float2* er = reinterpret_cast<const float2*>(emb + r * 10);
    float v[10];
#pragma unroll
    for (int k = 0; k < 5; ++k) { float2 t2 = er[k]; v[2 * k] = t2.x; v[2 * k + 1] = t2.y; }
    v8s lo8 = (v8s)0, hi8 = (v8s)0;
#pragma unroll
    for (int j = 0; j < 8; ++j) lo8[j] = (short)f2bf(v[j]);
    hi8[0] = (short)f2bf(v[8]);
    hi8[1] = (short)f2bf(v[9]);
    v8s* dst = reinterpret_cast<v8s*>(emb16 + r * 16);
    dst[0] = lo8;
    dst[1] = hi8;
  } else {
    int idx = (bid - 32) * 256 + threadIdx.x;   // (stage*11 + t)*64 + lane
    if (idx >= 3 * 11 * 64) return;
    int lane = idx & 63, rest = idx >> 6;
    int t = rest % 11, stage = rest / 11;
    const float* W = (stage == 0) ? w1 : (stage == 1) ? w2 : w3;
    int col = lane & 15;
    int kh = 2 * t + (lane >> 5);
    int wi0 = ((lane >> 4) & 1) * 8;
#pragma unroll
    for (int j = 0; j < 8; ++j) {
      int wi = wi0 + j;
      int kw = wi - col + 10;
      float v = (wi < 10 && col < 10 && kw >= 0 && kw < 22) ? W[kh * 22 + kw] : 0.0f;
      bh[idx * 8 + j] = f2bf(v);
    }
  }
}

// ---------------------------------------------------------------------------
// Packed-pair (two channels per u32, f16x2) bitonic primitives (r12-verified).
// ---------------------------------------------------------------------------
__device__ __forceinline__ unsigned h2max_u(unsigned a, unsigned b) {
  hf2 r = __builtin_elementwise_max(__builtin_bit_cast(hf2, a),
                                    __builtin_bit_cast(hf2, b));
  return __builtin_bit_cast(unsigned, r);
}
__device__ __forceinline__ unsigned h2min_u(unsigned a, unsigned b) {
  hf2 r = __builtin_elementwise_min(__builtin_bit_cast(hf2, a),
                                    __builtin_bit_cast(hf2, b));
  return __builtin_bit_cast(unsigned, r);
}
__device__ __forceinline__ unsigned bsort64_h2(unsigned v, int lane) {
#pragma unroll
  for (int k = 2; k <= 64; k <<= 1) {
#pragma unroll
    for (int j = k >> 1; j > 0; j >>= 1) {
      unsigned o = __shfl_xor(v, j, 64);
      bool keepmax = (((lane & k) == 0) == ((lane & j) == 0));
      unsigned mx = h2max_u(v, o), mn = h2min_u(v, o);
      v = keepmax ? mx : mn;
    }
  }
  return v;
}
__device__ __forceinline__ unsigned bmerge64_h2(unsigned a, unsigned b, int lane) {
  unsigned rb = __shfl(b, 63 - lane, 64);
  unsigned m = h2max_u(a, rb);
#pragma unroll
  for (int j = 32; j > 0; j >>= 1) {
    unsigned o = __shfl_xor(m, j, 64);
    unsigned mx = h2max_u(m, o), mn = h2min_u(m, o);
    m = ((lane & j) == 0) ? mx : mn;
  }
  return m;
}

// ---------------------------------------------------------------------------
// Fused 3-layer conv via bf16 MFMA (r18 structure; 40B row stride).
// Row r occupies ushorts [r*20, r*20+16): elems 0-9 real, 10-15 stored ZERO
// (A-pad; B rows for wi>=10 are zero so any finite value is exact — zeros
// also serve the hi-fragment's upper b64). 10-dword stride -> 16 distinct
// start banks (gcd(10,32)=2): conflict-free b64s vs r18's period-8 b128s.
// A-fragment = TWO ds_read_b64 sharing ONE vaddr (immediate offset:0/+8):
// zero extra address VALU — the r14/r19 regression trap avoided.
// ---------------------------------------------------------------------------
__global__ __launch_bounds__(512, 6) void conv_fused_kernel(
    const int* __restrict__ inputs, const unsigned short* __restrict__ emb16,
    const float* __restrict__ b1, const float* __restrict__ b2,
    const float* __restrict__ b3,
    const unsigned short* __restrict__ bh,
    unsigned* __restrict__ candp /* [NBS*5][NCHK][50] packed */) {
  __shared__ unsigned short plane[ROWS * RS];   // 21.4 KB

  int blk = blockIdx.x;
  int bs = blk / NCHK;
  int chunk = blk - bs * NCHK;
  int base = chunk * CHUNK;
  int tid = threadIdx.x;
  int lane = tid & 63, wave = tid >> 6;

  // ---- gather: bf16 emb rows for seq [base-32, base+504), 4x b64/row ----
  const int* tokp = inputs + bs * LSEQ;
  for (int i = tid; i < ROWS; i += 512) {
    int seq = base - 32 + i;
    v4s a0 = (v4s)0, a1 = (v4s)0, a2 = (v4s)0;
    if ((unsigned)seq < (unsigned)LSEQ) {
      int tok = tokp[seq];
      v8s lo8 = *reinterpret_cast<const v8s*>(emb16 + tok * 16);
      a0 = __builtin_shufflevector(lo8, lo8, 0, 1, 2, 3);
      a1 = __builtin_shufflevector(lo8, lo8, 4, 5, 6, 7);
      a2 = *reinterpret_cast<const v4s*>(emb16 + tok * 16 + 8);  // [e8,e9,0,0]
    }
    unsigned short* rp = &plane[i * RS];
    *reinterpret_cast<v4s*>(rp + 0) = a0;
    *reinterpret_cast<v4s*>(rp + 4) = a1;
    *reinterpret_cast<v4s*>(rp + 8) = a2;
    *reinterpret_cast<v4s*>(rp + 12) = (v4s)0;   // elems 12-15 = A-pad zeros
  }
  __syncthreads();

  // lane-constant A address: row (l&15)+(l>>5)+22 (incl +32 plane offset,
  // -10 kh shift), elem offset wi0 = ((l>>4)&1)*8.
  const int laneA = ((lane & 15) + (lane >> 5) + 22) * RS + ((lane >> 4) & 1) * 8;
  const int col = lane & 15;
  const int rbase = (lane >> 4) * 4;

#pragma unroll 1
  for (int stage = 0; stage < 3; ++stage) {
    const int lo = (stage == 0) ? -20 : (stage == 1) ? -10 : 0;
    const int ntiles = (stage == 0) ? 32 : (stage == 1) ? 30 : 28;
    const float bias = (stage == 0) ? b1[0] : (stage == 1) ? b2[0] : b3[0];
    const int nt = (ntiles - wave + 7) >> 3;     // tiles wave+8m, m<nt

    v4f acc[4];
#pragma unroll
    for (int m = 0; m < 4; ++m)
#pragma unroll
      for (int j = 0; j < 4; ++j) acc[m][j] = 0.0f;

    const v8s* bhf = reinterpret_cast<const v8s*>(bh) + (stage * 11) * 64 + lane;
    v8s bhc = bhf[0];

#pragma unroll 1
    for (int t = 0; t < 11; ++t) {
      v8s bhn = bhc;
      if (t < 10) bhn = bhf[(t + 1) * 64];
      const int toff = laneA + t * 2 * RS;
#pragma unroll
      for (int m = 0; m < 4; ++m) {
        if (m < nt) {
          int r0 = lo + (wave + 8 * m) * 16;
          const unsigned short* ap = &plane[toff + r0 * RS];
          v4s alo = *reinterpret_cast<const v4s*>(ap);       // offset:0
          v4s ahi = *reinterpret_cast<const v4s*>(ap + 4);   // offset:+8B
          v8s a = __builtin_shufflevector(alo, ahi, 0, 1, 2, 3, 4, 5, 6, 7);
          acc[m] = __builtin_amdgcn_mfma_f32_16x16x32_bf16(a, bhc, acc[m], 0, 0, 0);
        }
      }
      bhc = bhn;
    }
    __syncthreads();   // all reads complete before in-place writes

#pragma unroll
    for (int m = 0; m < 4; ++m) {
      if (m < nt) {
        int r0 = lo + (wave + 8 * m) * 16;
#pragma unroll
        for (int j = 0; j < 4; ++j) {
          int rloc = r0 + rbase + j;
          int seq = base + rloc;
          unsigned short us = cvt_bf16(fmaxf(acc[m][j] + bias, 0.0f));
          bool ok = (col < 10) && ((unsigned)seq < (unsigned)LSEQ);
          if (col < 10)
            plane[(rloc + 32) * RS + col] = ok ? us : (unsigned short)0;
        }
      }
    }
    __syncthreads();
  }

  // ---- per-chunk exact top-50, one packed channel-pair stream per wave ----
  if (wave < 5) {
    int p = wave;                              // cols 2p, 2p+1
    unsigned x[7];
#pragma unroll
    for (int s = 0; s < 7; ++s) {
      unsigned w = *reinterpret_cast<const unsigned*>(
          &plane[(32 + s * 64 + lane) * RS + 2 * p]);
      float flo = __uint_as_float(w << 16);          // bf16 lo -> f32 (exact)
      float fhi = __uint_as_float(w & 0xFFFF0000u);  // bf16 hi -> f32 (exact)
      hf2 h;
      h[0] = (_Float16)flo;                          // f32 -> f16 (exact here)
      h[1] = (_Float16)fhi;
      x[s] = __builtin_bit_cast(unsigned, h);
    }
#pragma unroll
    for (int s = 0; s < 7; ++s) x[s] = bsort64_h2(x[s], lane);
    unsigned y0 = bmerge64_h2(x[0], x[1], lane);
    unsigned y1 = bmerge64_h2(x[2], x[3], lane);
    unsigned y2 = bmerge64_h2(x[4], x[5], lane);
    unsigned z0 = bmerge64_h2(y0, y1, lane);
    unsigned z1 = bmerge64_h2(y2, x[6], lane);
    unsigned t  = bmerge64_h2(z0, z1, lane);
    if (lane < 50)
      candp[((bs * 5 + p) * NCHK + chunk) * 50 + lane] = t;
  }
}

// ---------------------------------------------------------------------------
// MHA with fused candidate merge (r18-verified, byte-identical): batched
// independent loads then pure-VALU 36-step bitonic-merge chain (exact).
// ---------------------------------------------------------------------------
__global__ __launch_bounds__(256) void mha_kernel(
    const unsigned* __restrict__ candp,
    const float* __restrict__ wq, const float* __restrict__ bq,
    const float* __restrict__ wk, const float* __restrict__ bk,
    const float* __restrict__ wv, const float* __restrict__ bv,
    const float* __restrict__ wo, const float* __restrict__ bo,
    const float* __restrict__ wf, const float* __restrict__ bf,
    float* __restrict__ out) {
  __shared__ float f[2][50][10];
  __shared__ float Qm[50][2][10];
  __shared__ float Km[50][2][10];
  __shared__ float Vm[50][2][10];
  __shared__ float A2[2][50][50];
  __shared__ float Abar[2][50];
  __shared__ float OS[2][10];
  __shared__ float rr[10];

  int blk = blockIdx.x, b = blk >> 1, dir = blk & 1;
  int qs = dir, ks = dir ^ 1;
  int tid = threadIdx.x;
  int lane = tid & 63, wave = tid >> 6;

  // ---- merge: stream s = s2*5 + p (sequence bs = 2b + s2, channels 2p,2p+1)
  for (int s = wave; s < 10; s += 4) {
    int s2 = s / 5, p = s - s2 * 5;
    int bs = 2 * b + s2;
    const unsigned* src = candp + ((bs * 5 + p) * NCHK) * 50;
    unsigned v[NCHK];
    if (lane < 50) {
#pragma unroll
      for (int c = 0; c < NCHK; ++c) v[c] = src[c * 50 + lane];   // independent
    } else {
#pragma unroll
      for (int c = 0; c < NCHK; ++c) v[c] = 0u;
    }
    unsigned acc = v[0];
#pragma unroll
    for (int c = 1; c < NCHK; ++c)
      acc = bmerge64_h2(acc, v[c], lane);      // pure-VALU chain
    if (lane < 50) {
      hf2 h = __builtin_bit_cast(hf2, acc);
      f[s2][lane][2 * p + 0] = (float)h[0];
      f[s2][lane][2 * p + 1] = (float)h[1];
    }
  }
  __syncthreads();

  for (int i = tid; i < 1000; i += 256) {
    int q = i / 20, rem = i - q * 20;
    int h = rem / 10, e = rem - h * 10;
    const float* fq = f[qs][q];
    const float* fk = f[ks][q];
    float aq = bq[h * 10 + e], ak = bk[h * 10 + e], av = bv[h * 10 + e];
#pragma unroll
    for (int dd = 0; dd < 10; ++dd) {
      int wIdx = dd * 20 + h * 10 + e;
      aq = fmaf(fq[dd], wq[wIdx], aq);
      ak = fmaf(fk[dd], wk[wIdx], ak);
      av = fmaf(fk[dd], wv[wIdx], av);
    }
    Qm[q][h][e] = aq; Km[q][h][e] = ak; Vm[q][h][e] = av;
  }
  __syncthreads();

  for (int row = tid; row < 100; row += 256) {
    int h = row / 50, q = row - h * 50;
    const float* Qr = Qm[q][h];
    float lg[50], m = -1e30f;
#pragma unroll
    for (int s = 0; s < 50; ++s) {
      const float* Kr = Km[s][h];
      float t = 0.0f;
#pragma unroll
      for (int e = 0; e < 10; ++e) t = fmaf(Qr[e], Kr[e], t);
      t *= 0.31622776601683794f;   // 1/sqrt(10)
      lg[s] = t; m = fmaxf(m, t);
    }
    float sum = 0.0f;
#pragma unroll
    for (int s = 0; s < 50; ++s) { float p = __expf(lg[s] - m); lg[s] = p; sum += p; }
    float inv = 1.0f / sum;
#pragma unroll
    for (int s = 0; s < 50; ++s) A2[h][q][s] = lg[s] * inv;
  }
  __syncthreads();

  for (int i = tid; i < 100; i += 256) {
    int h = i / 50, s = i - h * 50;
    float t = 0.0f;
#pragma unroll
    for (int q = 0; q < 50; ++q) t += A2[h][q][s];
    Abar[h][s] = t;
  }
  __syncthreads();
  if (tid < 20) {
    int h = tid / 10, e = tid - h * 10;
    float t = 0.0f;
#pragma unroll
    for (int s = 0; s < 50; ++s) t += Abar[h][s] * Vm[s][h][e];
    OS[h][e] = t;
  }
  __syncthreads();
  if (tid < 10) {
    int dc = tid;
    float t = 50.0f * bo[dc];
#pragma unroll
    for (int h = 0; h < 2; ++h)
#pragma unroll
      for (int e = 0; e < 10; ++e) t = fmaf(OS[h][e], wo[h * 100 + e * 10 + dc], t);
    rr[dc] = t;
  }
  __syncthreads();
  if (tid == 0) {
    float l0 = bf[0], l1 = bf[1];
#pragma unroll
    for (int dd = 0; dd < 10; ++dd) {
      l0 = fmaf(rr[dd], wf[dd * 2 + 0], l0);
      l1 = fmaf(rr[dd], wf[dd * 2 + 1], l1);
    }
    float m = fmaxf(l0, l1);
    float e0 = expf(l0 - m), e1 = expf(l1 - m);
    float inv = 1.0f / (e0 + e1);
    out[(b * 2 + dir) * 2 + 0] = e0 * inv;
    out[(b * 2 + dir) * 2 + 1] = e1 * inv;
  }
}

// ---------------------------------------------------------------------------
extern "C" void kernel_launch(void* const* d_in, const int* in_sizes, int n_in,
                              void* d_out, int out_size, void* d_ws, size_t ws_size,
                              hipStream_t stream) {
  const int*   inputs = (const int*)d_in[0];
  const float* emb = (const float*)d_in[1];
  const float* w1 = (const float*)d_in[2];
  const float* b1 = (const float*)d_in[3];
  const float* w2 = (const float*)d_in[4];
  const float* b2 = (const float*)d_in[5];
  const float* w3 = (const float*)d_in[6];
  const float* b3 = (const float*)d_in[7];
  const float* wq = (const float*)d_in[8];
  const float* bq = (const float*)d_in[9];
  const float* wk = (const float*)d_in[10];
  const float* bk = (const float*)d_in[11];
  const float* wv = (const float*)d_in[12];
  const float* bv = (const float*)d_in[13];
  const float* wo = (const float*)d_in[14];
  const float* bo = (const float*)d_in[15];
  const float* wf = (const float*)d_in[16];
  const float* bf = (const float*)d_in[17];
  float* out = (float*)d_out;

  unsigned* candp = (unsigned*)((float*)d_ws + 32768);   // 64*5*37*50 u32
  unsigned short* bh = (unsigned short*)((float*)d_ws + 1216768);   // 16896 u16
  unsigned short* emb16 = bh + 16896;                 // 8001*16 u16 (16B-aligned)

  // 41 blocks: 32 emb + 9 bfrag (2112 entries).
  hipLaunchKernelGGL(prep_kernel, dim3(41), dim3(256), 0, stream,
                     emb, w1, w2, w3, emb16, bh);
  hipLaunchKernelGGL(conv_fused_kernel, dim3(NBS * NCHK), dim3(512), 0, stream,
                     inputs, emb16, b1, b2, b3, bh, candp);
  hipLaunchKernelGGL(mha_kernel, dim3(NBS), dim3(256), 0, stream,
                     candp, wq, bq, wk, bk, wv, bv, wo, bo, wf, bf, out);
}

// Round 21
// 115.088 us; speedup vs baseline: 1.1077x; 1.0342x over previous
//
#include <hip/hip_runtime.h>
#include <hip/hip_bf16.h>

#define LSEQ   16384
#define BATCH  32
#define NBS    64              // B*2 sequences
#define NW     8000
#define CHUNK  448             // output rows per block
#define NCHK   37              // ceil(16384/448)
#define ROWS   536             // LDS plane rows: seq [base-32, base+504)
#define RS     24              // row stride in ushorts (48 B: 16 bf16 data + 8 pad)

typedef short v8s __attribute__((ext_vector_type(8)));   // 8 bf16 = 4 VGPR
typedef float v4f __attribute__((ext_vector_type(4)));   // MFMA acc
typedef _Float16 hf2 __attribute__((ext_vector_type(2)));  // packed f16 pair

__device__ __forceinline__ unsigned short f2bf(float f) {   // RTNE f32->bf16
  unsigned u = __float_as_uint(f);
  unsigned r = u + 0x7FFFu + ((u >> 16) & 1u);
  return (unsigned short)(r >> 16);
}
__device__ __forceinline__ unsigned short cvt_bf16(float v) {  // HW cvt
  __hip_bfloat16 hb = __float2bfloat16(v);
  unsigned short us;
  __builtin_memcpy(&us, &hb, 2);
  return us;
}

// ---------------------------------------------------------------------------
// Prep (r13/r17/r18-verified): blocks 0..31 build bf16 emb table [NW+1][16];
// blocks 32..40 build MFMA B-fragments (3*11*64 = 2112 entries -> 9 blocks).
// B[k=kh*16+wi][n] = W[kh][wi-n+10] (0 outside / n>=10); B-operand layout:
// lane l holds B[k][col=l&15], kh=2t+(l>>5), wi0=((l>>4)&1)*8, j=0..7.
// ---------------------------------------------------------------------------
__global__ __launch_bounds__(256) void prep_kernel(
    const float* __restrict__ emb, const float* __restrict__ w1,
    const float* __restrict__ w2, const float* __restrict__ w3,
    unsigned short* __restrict__ emb16, unsigned short* __restrict__ bh) {
  int bid = blockIdx.x;
  if (bid < 32) {
    int r = bid * 256 + threadIdx.x;
    if (r > NW) return;
    const float2* er = reinterpret_cast<const float2*>(emb + r * 10);
    float v[10];
#pragma unroll
    for (int k = 0; k < 5; ++k) { float2 t2 = er[k]; v[2 * k] = t2.x; v[2 * k + 1] = t2.y; }
    v8s lo8 = (v8s)0, hi8 = (v8s)0;
#pragma unroll
    for (int j = 0; j < 8; ++j) lo8[j] = (short)f2bf(v[j]);
    hi8[0] = (short)f2bf(v[8]);
    hi8[1] = (short)f2bf(v[9]);
    v8s* dst = reinterpret_cast<v8s*>(emb16 + r * 16);
    dst[0] = lo8;
    dst[1] = hi8;
  } else {
    int idx = (bid - 32) * 256 + threadIdx.x;   // (stage*11 + t)*64 + lane
    if (idx >= 3 * 11 * 64) return;
    int lane = idx & 63, rest = idx >> 6;
    int t = rest % 11, stage = rest / 11;
    const float* W = (stage == 0) ? w1 : (stage == 1) ? w2 : w3;
    int col = lane & 15;
    int kh = 2 * t + (lane >> 5);
    int wi0 = ((lane >> 4) & 1) * 8;
#pragma unroll
    for (int j = 0; j < 8; ++j) {
      int wi = wi0 + j;
      int kw = wi - col + 10;
      float v = (wi < 10 && col < 10 && kw >= 0 && kw < 22) ? W[kh * 22 + kw] : 0.0f;
      bh[idx * 8 + j] = f2bf(v);
    }
  }
}

// ---------------------------------------------------------------------------
// Packed-pair (two channels per u32, f16x2) bitonic primitives (r12-verified).
// ---------------------------------------------------------------------------
__device__ __forceinline__ unsigned h2max_u(unsigned a, unsigned b) {
  hf2 r = __builtin_elementwise_max(__builtin_bit_cast(hf2, a),
                                    __builtin_bit_cast(hf2, b));
  return __builtin_bit_cast(unsigned, r);
}
__device__ __forceinline__ unsigned h2min_u(unsigned a, unsigned b) {
  hf2 r = __builtin_elementwise_min(__builtin_bit_cast(hf2, a),
                                    __builtin_bit_cast(hf2, b));
  return __builtin_bit_cast(unsigned, r);
}
__device__ __forceinline__ unsigned bsort64_h2(unsigned v, int lane) {
#pragma unroll
  for (int k = 2; k <= 64; k <<= 1) {
#pragma unroll
    for (int j = k >> 1; j > 0; j >>= 1) {
      unsigned o = __shfl_xor(v, j, 64);
      bool keepmax = (((lane & k) == 0) == ((lane & j) == 0));
      unsigned mx = h2max_u(v, o), mn = h2min_u(v, o);
      v = keepmax ? mx : mn;
    }
  }
  return v;
}
__device__ __forceinline__ unsigned bmerge64_h2(unsigned a, unsigned b, int lane) {
  unsigned rb = __shfl(b, 63 - lane, 64);
  unsigned m = h2max_u(a, rb);
#pragma unroll
  for (int j = 32; j > 0; j >>= 1) {
    unsigned o = __shfl_xor(m, j, 64);
    unsigned mx = h2max_u(m, o), mn = h2min_u(m, o);
    m = ((lane & j) == 0) ? mx : mn;
  }
  return m;
}

// ---------------------------------------------------------------------------
// Fused 3-layer conv via bf16 MFMA + packed-pair bitonic top-50
// (r13/r17/r18-verified, byte-identical). Final configuration: three
// restructurings of the A-read path (r14 dense-K, r19 split-K, r20
// stride-20) all regressed vs this layout — its ~2-way-average bank
// aliasing hides under idle VALU slots, while every alternative pays more
// in issue count / marshaling than it saves in conflicts.
// ---------------------------------------------------------------------------
__global__ __launch_bounds__(512, 6) void conv_fused_kernel(
    const int* __restrict__ inputs, const unsigned short* __restrict__ emb16,
    const float* __restrict__ b1, const float* __restrict__ b2,
    const float* __restrict__ b3,
    const unsigned short* __restrict__ bh,
    unsigned* __restrict__ candp /* [NBS*5][NCHK][50] packed */) {
  __shared__ unsigned short plane[ROWS * RS];   // 25.7 KB

  int blk = blockIdx.x;
  int bs = blk / NCHK;
  int chunk = blk - bs * NCHK;
  int base = chunk * CHUNK;
  int tid = threadIdx.x;
  int lane = tid & 63, wave = tid >> 6;

  // ---- gather: copy bf16 emb rows for seq [base-32, base+504) ----
  const int* tokp = inputs + bs * LSEQ;
  for (int i = tid; i < ROWS; i += 512) {
    int seq = base - 32 + i;
    v8s lo8 = (v8s)0, hi8 = (v8s)0;
    if ((unsigned)seq < (unsigned)LSEQ) {
      int tok = tokp[seq];
      const v8s* er = reinterpret_cast<const v8s*>(emb16 + tok * 16);
      lo8 = er[0];
      hi8 = er[1];
    }
    *reinterpret_cast<v8s*>(&plane[i * RS + 0]) = lo8;
    *reinterpret_cast<v8s*>(&plane[i * RS + 8]) = hi8;
  }
  __syncthreads();

  // lane-constant A address part: row (l&15)+(l>>5)+22 (incl +32 plane offset,
  // -10 kh shift), elem offset wi0 = ((l>>4)&1)*8.
  const int laneA = ((lane & 15) + (lane >> 5) + 22) * RS + ((lane >> 4) & 1) * 8;
  const int col = lane & 15;
  const int rbase = (lane >> 4) * 4;

#pragma unroll 1
  for (int stage = 0; stage < 3; ++stage) {
    const int lo = (stage == 0) ? -20 : (stage == 1) ? -10 : 0;
    const int ntiles = (stage == 0) ? 32 : (stage == 1) ? 30 : 28;
    const float bias = (stage == 0) ? b1[0] : (stage == 1) ? b2[0] : b3[0];
    const int nt = (ntiles - wave + 7) >> 3;     // tiles wave+8m, m<nt

    v4f acc[4];
#pragma unroll
    for (int m = 0; m < 4; ++m)
#pragma unroll
      for (int j = 0; j < 4; ++j) acc[m][j] = 0.0f;

    const v8s* bhf = reinterpret_cast<const v8s*>(bh) + (stage * 11) * 64 + lane;
    v8s bhc = bhf[0];

#pragma unroll 1
    for (int t = 0; t < 11; ++t) {
      v8s bhn = bhc;
      if (t < 10) bhn = bhf[(t + 1) * 64];
      const int toff = laneA + t * 2 * RS;
#pragma unroll
      for (int m = 0; m < 4; ++m) {
        if (m < nt) {
          int r0 = lo + (wave + 8 * m) * 16;
          v8s a = *reinterpret_cast<const v8s*>(&plane[toff + r0 * RS]);
          acc[m] = __builtin_amdgcn_mfma_f32_16x16x32_bf16(a, bhc, acc[m], 0, 0, 0);
        }
      }
      bhc = bhn;
    }
    __syncthreads();   // all reads complete before in-place writes

#pragma unroll
    for (int m = 0; m < 4; ++m) {
      if (m < nt) {
        int r0 = lo + (wave + 8 * m) * 16;
#pragma unroll
        for (int j = 0; j < 4; ++j) {
          int rloc = r0 + rbase + j;
          int seq = base + rloc;
          unsigned short us = cvt_bf16(fmaxf(acc[m][j] + bias, 0.0f));
          bool ok = (col < 10) && ((unsigned)seq < (unsigned)LSEQ);
          plane[(rloc + 32) * RS + col] = ok ? us : (unsigned short)0;
        }
      }
    }
    __syncthreads();
  }

  // ---- per-chunk exact top-50, one packed channel-pair stream per wave ----
  if (wave < 5) {
    int p = wave;                              // cols 2p, 2p+1
    unsigned x[7];
#pragma unroll
    for (int s = 0; s < 7; ++s) {
      unsigned w = *reinterpret_cast<const unsigned*>(
          &plane[(32 + s * 64 + lane) * RS + 2 * p]);
      float flo = __uint_as_float(w << 16);          // bf16 lo -> f32 (exact)
      float fhi = __uint_as_float(w & 0xFFFF0000u);  // bf16 hi -> f32 (exact)
      hf2 h;
      h[0] = (_Float16)flo;                          // f32 -> f16 (exact here)
      h[1] = (_Float16)fhi;
      x[s] = __builtin_bit_cast(unsigned, h);
    }
#pragma unroll
    for (int s = 0; s < 7; ++s) x[s] = bsort64_h2(x[s], lane);
    unsigned y0 = bmerge64_h2(x[0], x[1], lane);
    unsigned y1 = bmerge64_h2(x[2], x[3], lane);
    unsigned y2 = bmerge64_h2(x[4], x[5], lane);
    unsigned z0 = bmerge64_h2(y0, y1, lane);
    unsigned z1 = bmerge64_h2(y2, x[6], lane);
    unsigned t  = bmerge64_h2(z0, z1, lane);
    if (lane < 50)
      candp[((bs * 5 + p) * NCHK + chunk) * 50 + lane] = t;
  }
}

// ---------------------------------------------------------------------------
// MHA with fused candidate merge (r18-verified, byte-identical): batched
// independent loads then pure-VALU 36-step bitonic-merge chain (exact).
// ---------------------------------------------------------------------------
__global__ __launch_bounds__(256) void mha_kernel(
    const unsigned* __restrict__ candp,
    const float* __restrict__ wq, const float* __restrict__ bq,
    const float* __restrict__ wk, const float* __restrict__ bk,
    const float* __restrict__ wv, const float* __restrict__ bv,
    const float* __restrict__ wo, const float* __restrict__ bo,
    const float* __restrict__ wf, const float* __restrict__ bf,
    float* __restrict__ out) {
  __shared__ float f[2][50][10];
  __shared__ float Qm[50][2][10];
  __shared__ float Km[50][2][10];
  __shared__ float Vm[50][2][10];
  __shared__ float A2[2][50][50];
  __shared__ float Abar[2][50];
  __shared__ float OS[2][10];
  __shared__ float rr[10];

  int blk = blockIdx.x, b = blk >> 1, dir = blk & 1;
  int qs = dir, ks = dir ^ 1;
  int tid = threadIdx.x;
  int lane = tid & 63, wave = tid >> 6;

  // ---- merge: stream s = s2*5 + p (sequence bs = 2b + s2, channels 2p,2p+1)
  for (int s = wave; s < 10; s += 4) {
    int s2 = s / 5, p = s - s2 * 5;
    int bs = 2 * b + s2;
    const unsigned* src = candp + ((bs * 5 + p) * NCHK) * 50;
    unsigned v[NCHK];
    if (lane < 50) {
#pragma unroll
      for (int c = 0; c < NCHK; ++c) v[c] = src[c * 50 + lane];   // independent
    } else {
#pragma unroll
      for (int c = 0; c < NCHK; ++c) v[c] = 0u;
    }
    unsigned acc = v[0];
#pragma unroll
    for (int c = 1; c < NCHK; ++c)
      acc = bmerge64_h2(acc, v[c], lane);      // pure-VALU chain
    if (lane < 50) {
      hf2 h = __builtin_bit_cast(hf2, acc);
      f[s2][lane][2 * p + 0] = (float)h[0];
      f[s2][lane][2 * p + 1] = (float)h[1];
    }
  }
  __syncthreads();

  for (int i = tid; i < 1000; i += 256) {
    int q = i / 20, rem = i - q * 20;
    int h = rem / 10, e = rem - h * 10;
    const float* fq = f[qs][q];
    const float* fk = f[ks][q];
    float aq = bq[h * 10 + e], ak = bk[h * 10 + e], av = bv[h * 10 + e];
#pragma unroll
    for (int dd = 0; dd < 10; ++dd) {
      int wIdx = dd * 20 + h * 10 + e;
      aq = fmaf(fq[dd], wq[wIdx], aq);
      ak = fmaf(fk[dd], wk[wIdx], ak);
      av = fmaf(fk[dd], wv[wIdx], av);
    }
    Qm[q][h][e] = aq; Km[q][h][e] = ak; Vm[q][h][e] = av;
  }
  __syncthreads();

  for (int row = tid; row < 100; row += 256) {
    int h = row / 50, q = row - h * 50;
    const float* Qr = Qm[q][h];
    float lg[50], m = -1e30f;
#pragma unroll
    for (int s = 0; s < 50; ++s) {
      const float* Kr = Km[s][h];
      float t = 0.0f;
#pragma unroll
      for (int e = 0; e < 10; ++e) t = fmaf(Qr[e], Kr[e], t);
      t *= 0.31622776601683794f;   // 1/sqrt(10)
      lg[s] = t; m = fmaxf(m, t);
    }
    float sum = 0.0f;
#pragma unroll
    for (int s = 0; s < 50; ++s) { float p = __expf(lg[s] - m); lg[s] = p; sum += p; }
    float inv = 1.0f / sum;
#pragma unroll
    for (int s = 0; s < 50; ++s) A2[h][q][s] = lg[s] * inv;
  }
  __syncthreads();

  for (int i = tid; i < 100; i += 256) {
    int h = i / 50, s = i - h * 50;
    float t = 0.0f;
#pragma unroll
    for (int q = 0; q < 50; ++q) t += A2[h][q][s];
    Abar[h][s] = t;
  }
  __syncthreads();
  if (tid < 20) {
    int h = tid / 10, e = tid - h * 10;
    float t = 0.0f;
#pragma unroll
    for (int s = 0; s < 50; ++s) t += Abar[h][s] * Vm[s][h][e];
    OS[h][e] = t;
  }
  __syncthreads();
  if (tid < 10) {
    int dc = tid;
    float t = 50.0f * bo[dc];
#pragma unroll
    for (int h = 0; h < 2; ++h)
#pragma unroll
      for (int e = 0; e < 10; ++e) t = fmaf(OS[h][e], wo[h * 100 + e * 10 + dc], t);
    rr[dc] = t;
  }
  __syncthreads();
  if (tid == 0) {
    float l0 = bf[0], l1 = bf[1];
#pragma unroll
    for (int dd = 0; dd < 10; ++dd) {
      l0 = fmaf(rr[dd], wf[dd * 2 + 0], l0);
      l1 = fmaf(rr[dd], wf[dd * 2 + 1], l1);
    }
    float m = fmaxf(l0, l1);
    float e0 = expf(l0 - m), e1 = expf(l1 - m);
    float inv = 1.0f / (e0 + e1);
    out[(b * 2 + dir) * 2 + 0] = e0 * inv;
    out[(b * 2 + dir) * 2 + 1] = e1 * inv;
  }
}

// ---------------------------------------------------------------------------
extern "C" void kernel_launch(void* const* d_in, const int* in_sizes, int n_in,
                              void* d_out, int out_size, void* d_ws, size_t ws_size,
                              hipStream_t stream) {
  const int*   inputs = (const int*)d_in[0];
  const float* emb = (const float*)d_in[1];
  const float* w1 = (const float*)d_in[2];
  const float* b1 = (const float*)d_in[3];
  const float* w2 = (const float*)d_in[4];
  const float* b2 = (const float*)d_in[5];
  const float* w3 = (const float*)d_in[6];
  const float* b3 = (const float*)d_in[7];
  const float* wq = (const float*)d_in[8];
  const float* bq = (const float*)d_in[9];
  const float* wk = (const float*)d_in[10];
  const float* bk = (const float*)d_in[11];
  const float* wv = (const float*)d_in[12];
  const float* bv = (const float*)d_in[13];
  const float* wo = (const float*)d_in[14];
  const float* bo = (const float*)d_in[15];
  const float* wf = (const float*)d_in[16];
  const float* bf = (const float*)d_in[17];
  float* out = (float*)d_out;

  unsigned* candp = (unsigned*)((float*)d_ws + 32768);   // 64*5*37*50 u32
  unsigned short* bh = (unsigned short*)((float*)d_ws + 1216768);   // 16896 u16
  unsigned short* emb16 = bh + 16896;                 // 8001*16 u16 (16B-aligned)

  // 41 blocks: 32 emb + 9 bfrag (2112 entries).
  hipLaunchKernelGGL(prep_kernel, dim3(41), dim3(256), 0, stream,
                     emb, w1, w2, w3, emb16, bh);
  hipLaunchKernelGGL(conv_fused_kernel, dim3(NBS * NCHK), dim3(512), 0, stream,
                     inputs, emb16, b1, b2, b3, bh, candp);
  hipLaunchKernelGGL(mha_kernel, dim3(NBS), dim3(256), 0, stream,
                     candp, wq, bq, wk, bk, wv, bv, wo, bo, wf, bf, out);
}